// Round 12
// baseline (1099.775 us; speedup 1.0000x reference)
//
#include <hip/hip_runtime.h>
#include <hip/hip_bf16.h>
#include <cstdint>
#include <cstddef>

// SelfAttentionV2: x[4096,1024] fp32; Wq/Wk/Wv [1024,1024] fp32.
// out = softmax(causal((x Wq^T)(x Wk^T)^T / 32)) @ (x Wv^T), fp32 out.
//
// GEMM structure (R8 ring + R10 reg-pipeline + FORCED MFMA/ds_read interleave):
// 256x256 tile, 8 waves, per-wave out 128x64 (acc[8][4]), BK=32, 3 LDS K-tile
// ring buffers (96KB). Per step s:
//   stage(s+2) [4 gload_lds -> buf(s+2)%3]
//   lgkmcnt(0) [frags(s) ready; reads of buf(s+1) from step s-1 drained]
//   sched_barrier(0)                       [rule 18]
//   vmcnt(4|0) [stage(s+1) landed] ; s_barrier [skipped at last step]
//   setprio(1)
//   [4 MFMA][SB0][3 ds_read next-frags][SB0][4 MFMA][SB0][3 reads]...[16 MFMA]
//   setprio(0)
// The SB0 fences pin ds_reads INSIDE the MFMA cluster so the LDS port burst
// (96 b128 reads/CU ~1150cyc) overlaps the matrix pipe (~1240cyc) instead of
// serializing after it (R10 null: compiler sank the reads below the MFMAs).
// Hazard proof: reads of buf X issue during step X-1, drain at lgkmcnt(0) top
// of step X before barrier(X); stage overwriting buf X issues at step X+1
// after every wave passed barrier(X). Even/odd frag sets statically named.
// LDS rows 64B; XOR swizzle byte ^= ((byte>>9)&1)<<5 on global SOURCE at
// stage (global_load_lds writes linearly) and on ds_read addrs.

#define SEQQ 4096
#define DDIM 1024

typedef __bf16 bf16x8 __attribute__((ext_vector_type(8)));
typedef float f32x4 __attribute__((ext_vector_type(4)));

__device__ __forceinline__ unsigned short f2bf(float f) {
  unsigned int u = __builtin_bit_cast(unsigned int, f);
  unsigned int r = u + 0x7FFFu + ((u >> 16) & 1u);  // RNE; -inf stays -inf
  return (unsigned short)(r >> 16);
}

__device__ __forceinline__ void gload_lds16(const void* g, void* lds) {
  __builtin_amdgcn_global_load_lds(
      (__attribute__((address_space(1))) void*)(uintptr_t)g,
      (__attribute__((address_space(3))) void*)(uintptr_t)lds, 16, 0, 0);
}

// ---- fused fp32 -> bf16 conversion (x, Wq*1/32, Wk, Wv) ----
__global__ __launch_bounds__(256) void cvt_all(const float* __restrict__ x,
                                               const float* __restrict__ Wq,
                                               const float* __restrict__ Wk,
                                               const float* __restrict__ Wv,
                                               unsigned short* __restrict__ xb,
                                               unsigned short* __restrict__ Wcat) {
  int b = blockIdx.x;
  const float* src;
  unsigned short* dst;
  float scale = 1.0f;
  if (b < 4096) {
    src = x; dst = xb;
  } else if (b < 5120) {
    src = Wq; dst = Wcat; scale = 0.03125f; b -= 4096;
  } else if (b < 6144) {
    src = Wk; dst = Wcat + (1u << 20); b -= 5120;
  } else {
    src = Wv; dst = Wcat + (2u << 20); b -= 6144;
  }
  const int i = (b * 256 + threadIdx.x) * 4;
  const float4 v = *reinterpret_cast<const float4*>(src + i);
  ushort4 o;
  o.x = f2bf(v.x * scale);
  o.y = f2bf(v.y * scale);
  o.z = f2bf(v.z * scale);
  o.w = f2bf(v.w * scale);
  *reinterpret_cast<ushort4*>(dst + i) = o;
}

// ---- 256x256 GEMM core: LDS [3 buf][256 r][32 c] bf16 per operand ----
#define GEMM_PRE()                                                          \
  __shared__ unsigned short As[3][8192] __attribute__((aligned(16)));       \
  __shared__ unsigned short Bs[3][8192] __attribute__((aligned(16)));       \
  const int tid = threadIdx.x;                                              \
  const int wave = tid >> 6, lane = tid & 63;                               \
  const int wr = (wave >> 2) * 128, wc = (wave & 3) * 64;                   \
  f32x4 acc[8][4] = {};                                                     \
  int offA[8], offB[4];                                                     \
  {                                                                         \
    const int cb = (lane >> 4) * 16;                                        \
    const int rA = wr + (lane & 15);                                        \
    _Pragma("unroll")                                                       \
    for (int m = 0; m < 8; ++m) {                                           \
      int o = (rA + m * 16) * 64 + cb;                                      \
      offA[m] = o ^ (((o >> 9) & 1) << 5);                                  \
    }                                                                       \
    const int rB = wc + (lane & 15);                                        \
    _Pragma("unroll")                                                       \
    for (int n = 0; n < 4; ++n) {                                           \
      int o = (rB + n * 16) * 64 + cb;                                      \
      offB[n] = o ^ (((o >> 9) & 1) << 5);                                  \
    }                                                                       \
  }

#define SB0 __builtin_amdgcn_sched_barrier(0)

#define MM4(AC, BC, mm)                                                     \
  acc[mm][0] = __builtin_amdgcn_mfma_f32_16x16x32_bf16(AC[mm], BC[0],       \
                                                       acc[mm][0], 0, 0, 0);\
  acc[mm][1] = __builtin_amdgcn_mfma_f32_16x16x32_bf16(AC[mm], BC[1],       \
                                                       acc[mm][1], 0, 0, 0);\
  acc[mm][2] = __builtin_amdgcn_mfma_f32_16x16x32_bf16(AC[mm], BC[2],       \
                                                       acc[mm][2], 0, 0, 0);\
  acc[mm][3] = __builtin_amdgcn_mfma_f32_16x16x32_bf16(AC[mm], BC[3],       \
                                                       acc[mm][3], 0, 0, 0);

// One K-tile step. AC/BC: frags for THIS tile (in regs). AN/BN: set to fill
// with next tile's frags, interleaved into the MFMA cluster via SB0 fences.
#define GEMM_STEP(AC, BC, AN, BN, s)                                        \
  {                                                                         \
    if ((s) + 2 < nt) {                                                     \
      const int wb = (rb >= 1) ? rb - 1 : 2;                                \
      const int wofs2 = wb * 16384 + wofs;                                  \
      gload_lds16(pA0, ldsA + wofs2);                                       \
      gload_lds16(pA1, ldsA + wofs2 + 8192);                                \
      gload_lds16(pB0, ldsB + wofs2);                                       \
      gload_lds16(pB1, ldsB + wofs2 + 8192);                                \
      pA0 += 64; pA1 += 64; pB0 += 64; pB1 += 64;                           \
    }                                                                       \
    asm volatile("s_waitcnt lgkmcnt(0)" ::: "memory");                      \
    SB0;                                                                    \
    if ((s) + 2 < nt) {                                                     \
      asm volatile("s_waitcnt vmcnt(4)" ::: "memory");                      \
    } else if ((s) + 1 < nt) {                                              \
      asm volatile("s_waitcnt vmcnt(0)" ::: "memory");                      \
    }                                                                       \
    if ((s) + 1 < nt) asm volatile("s_barrier" ::: "memory");               \
    __builtin_amdgcn_s_setprio(1);                                          \
    if ((s) + 1 < nt) {                                                     \
      const int rbn = (rb == 2) ? 0 : rb + 1;                               \
      const int nofs = rbn * 16384;                                         \
      MM4(AC, BC, 0);                                                       \
      SB0;                                                                  \
      AN[0] = *(const bf16x8*)(ldsA + nofs + offA[0]);                      \
      AN[1] = *(const bf16x8*)(ldsA + nofs + offA[1]);                      \
      AN[2] = *(const bf16x8*)(ldsA + nofs + offA[2]);                      \
      SB0;                                                                  \
      MM4(AC, BC, 1);                                                       \
      SB0;                                                                  \
      AN[3] = *(const bf16x8*)(ldsA + nofs + offA[3]);                      \
      AN[4] = *(const bf16x8*)(ldsA + nofs + offA[4]);                      \
      AN[5] = *(const bf16x8*)(ldsA + nofs + offA[5]);                      \
      SB0;                                                                  \
      MM4(AC, BC, 2);                                                       \
      SB0;                                                                  \
      AN[6] = *(const bf16x8*)(ldsA + nofs + offA[6]);                      \
      AN[7] = *(const bf16x8*)(ldsA + nofs + offA[7]);                      \
      BN[0] = *(const bf16x8*)(ldsB + nofs + offB[0]);                      \
      SB0;                                                                  \
      MM4(AC, BC, 3);                                                       \
      SB0;                                                                  \
      BN[1] = *(const bf16x8*)(ldsB + nofs + offB[1]);                      \
      BN[2] = *(const bf16x8*)(ldsB + nofs + offB[2]);                      \
      BN[3] = *(const bf16x8*)(ldsB + nofs + offB[3]);                      \
      SB0;                                                                  \
      MM4(AC, BC, 4);                                                       \
      MM4(AC, BC, 5);                                                       \
      MM4(AC, BC, 6);                                                       \
      MM4(AC, BC, 7);                                                       \
    } else {                                                                \
      MM4(AC, BC, 0); MM4(AC, BC, 1); MM4(AC, BC, 2); MM4(AC, BC, 3);       \
      MM4(AC, BC, 4); MM4(AC, BC, 5); MM4(AC, BC, 6); MM4(AC, BC, 7);       \
    }                                                                       \
    __builtin_amdgcn_s_setprio(0);                                          \
    rb = (rb == 2) ? 0 : rb + 1;                                            \
  }

#define GEMM_LOOP(ABASE, LDA, BBASE, LDB, S0, S1)                           \
  do {                                                                      \
    const int nt = (S1) - (S0);                                             \
    const char *pA0, *pA1, *pB0, *pB1;                                      \
    {                                                                       \
      const size_t srow = wave * 16 + (lane >> 2);                          \
      const int scb = ((lane & 3) * 16) ^ (((lane >> 5) & 1) << 5);         \
      pA0 = (const char*)(ABASE) + srow * ((size_t)(LDA) * 2) +             \
            (size_t)(S0) * 64 + scb;                                        \
      pA1 = pA0 + (size_t)128 * ((size_t)(LDA) * 2);                        \
      pB0 = (const char*)(BBASE) + srow * ((size_t)(LDB) * 2) +             \
            (size_t)(S0) * 64 + scb;                                        \
      pB1 = pB0 + (size_t)128 * ((size_t)(LDB) * 2);                        \
    }                                                                       \
    char* ldsA = (char*)&As[0][0];                                          \
    char* ldsB = (char*)&Bs[0][0];                                          \
    const int wofs = wave * 1024;                                           \
    gload_lds16(pA0, ldsA + wofs);                                          \
    gload_lds16(pA1, ldsA + 8192 + wofs);                                   \
    gload_lds16(pB0, ldsB + wofs);                                          \
    gload_lds16(pB1, ldsB + 8192 + wofs);                                   \
    pA0 += 64; pA1 += 64; pB0 += 64; pB1 += 64;                             \
    if (nt > 1) {                                                           \
      gload_lds16(pA0, ldsA + 16384 + wofs);                                \
      gload_lds16(pA1, ldsA + 16384 + 8192 + wofs);                         \
      gload_lds16(pB0, ldsB + 16384 + wofs);                                \
      gload_lds16(pB1, ldsB + 16384 + 8192 + wofs);                         \
      pA0 += 64; pA1 += 64; pB0 += 64; pB1 += 64;                           \
      asm volatile("s_waitcnt vmcnt(4)" ::: "memory");                      \
    } else {                                                                \
      asm volatile("s_waitcnt vmcnt(0)" ::: "memory");                      \
    }                                                                       \
    asm volatile("s_barrier" ::: "memory");                                 \
    bf16x8 aE[8], bE[4], aO[8], bO[4];                                      \
    _Pragma("unroll")                                                       \
    for (int m = 0; m < 8; ++m) aE[m] = *(const bf16x8*)(ldsA + offA[m]);   \
    _Pragma("unroll")                                                       \
    for (int n = 0; n < 4; ++n) bE[n] = *(const bf16x8*)(ldsB + offB[n]);   \
    int rb = 0;                                                             \
    int s = 0;                                                              \
    for (; s + 1 < nt; s += 2) {                                            \
      GEMM_STEP(aE, bE, aO, bO, s);                                         \
      GEMM_STEP(aO, bO, aE, bE, s + 1);                                     \
    }                                                                       \
    if (s < nt) GEMM_STEP(aE, bE, aO, bO, s);                               \
  } while (0)

// ---- QKV: C[4096,3072] = xb @ Wcat^T; Q,K row-major; V transposed ----
__global__ __launch_bounds__(512, 1) void gemm_qkv(const unsigned short* __restrict__ X,
                                                   const unsigned short* __restrict__ W,
                                                   unsigned short* __restrict__ Qb,
                                                   unsigned short* __restrict__ Kb,
                                                   unsigned short* __restrict__ Vt) {
  GEMM_PRE();
  const int brow = blockIdx.y * 256, bcol = blockIdx.x * 256;
  GEMM_LOOP(X + (size_t)brow * DDIM, DDIM, W + (size_t)bcol * DDIM, DDIM, 0, 32);
  const int region = bcol >> 10;  // 0=Q 1=K 2=V
  const int lcol = bcol & 1023;
  const int c0 = wc + (lane & 15);
  const int r0 = wr + ((lane >> 4) << 2);
  if (region < 2) {
    unsigned short* dst = (region == 0) ? Qb : Kb;
#pragma unroll
    for (int m = 0; m < 8; ++m) {
      const int r = brow + r0 + m * 16;
#pragma unroll
      for (int n = 0; n < 4; ++n) {
        const int c = lcol + c0 + n * 16;
#pragma unroll
        for (int j = 0; j < 4; ++j)
          dst[(size_t)(r + j) * DDIM + c] = f2bf(acc[m][n][j]);
      }
    }
  } else {
#pragma unroll
    for (int m = 0; m < 8; ++m) {
      const int r = brow + r0 + m * 16;
#pragma unroll
      for (int n = 0; n < 4; ++n) {
        const int c = lcol + c0 + n * 16;
        ushort4 pk;
        pk.x = f2bf(acc[m][n][0]);
        pk.y = f2bf(acc[m][n][1]);
        pk.z = f2bf(acc[m][n][2]);
        pk.w = f2bf(acc[m][n][3]);
        *reinterpret_cast<ushort4*>(Vt + (size_t)c * SEQQ + r) = pk;
      }
    }
  }
}

// ---- QK^T: S = Qb @ Kb^T, lower-triangle 256-tiles, causal mask ----
__global__ __launch_bounds__(512, 1) void gemm_qkt(const unsigned short* __restrict__ Qb,
                                                   const unsigned short* __restrict__ Kb,
                                                   unsigned short* __restrict__ S) {
  const int bi = blockIdx.y, bj = blockIdx.x;
  if (bj > bi) return;
  GEMM_PRE();
  const int brow = bi * 256, bcol = bj * 256;
  GEMM_LOOP(Qb + (size_t)brow * DDIM, DDIM, Kb + (size_t)bcol * DDIM, DDIM, 0, 32);
  const int c0 = wc + (lane & 15);
  const int r0 = wr + ((lane >> 4) << 2);
#pragma unroll
  for (int m = 0; m < 8; ++m) {
    const int r = brow + r0 + m * 16;
#pragma unroll
    for (int n = 0; n < 4; ++n) {
      const int c = bcol + c0 + n * 16;
#pragma unroll
      for (int j = 0; j < 4; ++j) {
        unsigned short o = (c > r + j) ? (unsigned short)0xFF80  // -inf bf16
                                       : f2bf(acc[m][n][j]);
        S[(size_t)(r + j) * SEQQ + c] = o;
      }
    }
  }
}

// ---- row softmax over causal prefix (256-padded), in place ----
__global__ __launch_bounds__(256) void softmax_causal(unsigned short* __restrict__ S) {
  const int row = blockIdx.x;
  const int L = ((row >> 8) + 1) << 8;  // 256-padded: matches PV K-extent
  unsigned short* Srow = S + (size_t)row * SEQQ;
  __shared__ float red[4];
  const int tid = threadIdx.x;
  const int lane = tid & 63, wave = tid >> 6;

  float x[16];
  bool have[2];
  float m = -3.0e38f;
#pragma unroll
  for (int it = 0; it < 2; ++it) {
    const int j = tid * 8 + it * 2048;
    have[it] = (j < L);
    if (have[it]) {
      const uint4 v = *reinterpret_cast<const uint4*>(Srow + j);
      const unsigned u[4] = {v.x, v.y, v.z, v.w};
#pragma unroll
      for (int q = 0; q < 4; ++q) {
        x[it * 8 + q * 2] = __builtin_bit_cast(float, u[q] << 16);
        x[it * 8 + q * 2 + 1] = __builtin_bit_cast(float, u[q] & 0xFFFF0000u);
      }
#pragma unroll
      for (int q = 0; q < 8; ++q) m = fmaxf(m, x[it * 8 + q]);
    }
  }
#pragma unroll
  for (int o = 32; o; o >>= 1) m = fmaxf(m, __shfl_xor(m, o));
  if (lane == 0) red[wave] = m;
  __syncthreads();
  m = fmaxf(fmaxf(red[0], red[1]), fmaxf(red[2], red[3]));
  __syncthreads();

  float sum = 0.f;
#pragma unroll
  for (int it = 0; it < 2; ++it)
    if (have[it]) {
#pragma unroll
      for (int q = 0; q < 8; ++q) {
        x[it * 8 + q] = __expf(x[it * 8 + q] - m);  // exp(-inf)=0 for masked
        sum += x[it * 8 + q];
      }
    }
#pragma unroll
  for (int o = 32; o; o >>= 1) sum += __shfl_xor(sum, o);
  if (lane == 0) red[wave] = sum;
  __syncthreads();
  sum = red[0] + red[1] + red[2] + red[3];
  const float inv = 1.0f / sum;

#pragma unroll
  for (int it = 0; it < 2; ++it)
    if (have[it]) {
      const int j = tid * 8 + it * 2048;
      unsigned u[4];
#pragma unroll
      for (int q = 0; q < 4; ++q) {
        u[q] = (unsigned)f2bf(x[it * 8 + q * 2] * inv) |
               ((unsigned)f2bf(x[it * 8 + q * 2 + 1] * inv) << 16);
      }
      *reinterpret_cast<uint4*>(Srow + j) = make_uint4(u[0], u[1], u[2], u[3]);
    }
}

// ---- split-K helpers for PV (256-row blocks bi=0..15) ----
__device__ __forceinline__ int pv_nc(int bi) { return (bi >> 2) + 1; }
__device__ __forceinline__ int pv_rcbase(int bi) {
  const int g = bi >> 2, r = bi & 3;
  return 2 * g * (g - 1) + r * g;
}

// ---- PV: out/partials = P @ Vt^T, causal K-range, split-K ----
__global__ __launch_bounds__(512, 1) void gemm_pv_split(const unsigned short* __restrict__ P,
                                                        const unsigned short* __restrict__ Vt,
                                                        float* __restrict__ O,
                                                        float* __restrict__ part) {
  const int bj = blockIdx.x, bi = blockIdx.y, ck = blockIdx.z;
  const int nc = pv_nc(bi);
  if (ck >= nc) return;
  const int kt = (bi + 1) * 8;                  // K-tiles of 32 elems
  const int W = (kt + nc - 1) / nc;
  const int s0 = ck * W;
  const int s1 = min(s0 + W, kt);
  if (s0 >= s1) return;

  GEMM_PRE();
  const int brow = bi * 256, bcol = bj * 256;
  GEMM_LOOP(P + (size_t)brow * SEQQ, SEQQ, Vt + (size_t)bcol * SEQQ, SEQQ, s0, s1);
  const int c0 = wc + (lane & 15);
  const int r0 = wr + ((lane >> 4) << 2);
  if (ck == 0) {
#pragma unroll
    for (int m = 0; m < 8; ++m) {
      const int r = brow + r0 + m * 16;
#pragma unroll
      for (int n = 0; n < 4; ++n) {
        const int c = bcol + c0 + n * 16;
#pragma unroll
        for (int j = 0; j < 4; ++j)
          O[(size_t)(r + j) * DDIM + c] = acc[m][n][j];
      }
    }
  } else {
    float* tile = part + ((size_t)(pv_rcbase(bi) + (ck - 1)) * 4 + bj) * 65536;
#pragma unroll
    for (int m = 0; m < 8; ++m) {
      const int lr = r0 + m * 16;
#pragma unroll
      for (int n = 0; n < 4; ++n) {
        const int lc = c0 + n * 16;
#pragma unroll
        for (int j = 0; j < 4; ++j)
          tile[(lr + j) * 256 + lc] = acc[m][n][j];
      }
    }
  }
}

// ---- add partial tiles into out rows >= 1024 ----
__global__ __launch_bounds__(256) void reduce_pv(float* __restrict__ O,
                                                 const float* __restrict__ part) {
  const int idx = blockIdx.x * 256 + threadIdx.x;   // one float4 per thread
  const int r = 1024 + (idx >> 8);                  // 256 float4s per row
  const int cc = (idx & 255) * 4;
  const int bi = r >> 8;
  const int nparts = bi >> 2;                       // nc-1
  const int rcb = pv_rcbase(bi);
  const int bj = cc >> 8;
  const int lr = r & 255, lc = cc & 255;
  float4 acc = *reinterpret_cast<float4*>(O + (size_t)r * DDIM + cc);
  for (int k = 0; k < nparts; ++k) {
    const float4 p = *reinterpret_cast<const float4*>(
        part + ((size_t)(rcb + k) * 4 + bj) * 65536 + lr * 256 + lc);
    acc.x += p.x; acc.y += p.y; acc.z += p.z; acc.w += p.w;
  }
  *reinterpret_cast<float4*>(O + (size_t)r * DDIM + cc) = acc;
}

extern "C" void kernel_launch(void* const* d_in, const int* in_sizes, int n_in,
                              void* d_out, int out_size, void* d_ws, size_t ws_size,
                              hipStream_t stream) {
  (void)in_sizes; (void)n_in; (void)out_size; (void)ws_size;
  const float* x = (const float*)d_in[0];
  const float* Wq = (const float*)d_in[1];
  const float* Wk = (const float*)d_in[2];
  const float* Wv = (const float*)d_in[3];
  float* out = (float*)d_out;

  char* ws = (char*)d_ws;
  unsigned short* xb   = (unsigned short*)(ws);                        //  8 MB [4096,1024]
  unsigned short* Wcat = (unsigned short*)(ws + ((size_t)8 << 20));    //  6 MB [3072,1024]
  unsigned short* Qb   = (unsigned short*)(ws + ((size_t)14 << 20));   //  8 MB [4096,1024]
  unsigned short* Kb   = (unsigned short*)(ws + ((size_t)22 << 20));   //  8 MB [4096,1024]
  unsigned short* Vt   = (unsigned short*)(ws + ((size_t)30 << 20));   //  8 MB [1024,4096]
  unsigned short* S    = (unsigned short*)(ws + ((size_t)38 << 20));   // 32 MB [4096,4096]
  float* part = (float*)ws;  // 24 MB fp32 partials; reuses dead xb/Wcat/Qb/Kb region

  cvt_all<<<7168, 256, 0, stream>>>(x, Wq, Wk, Wv, xb, Wcat);
  gemm_qkv<<<dim3(12, 16), 512, 0, stream>>>(xb, Wcat, Qb, Kb, Vt);
  gemm_qkt<<<dim3(16, 16), 512, 0, stream>>>(Qb, Kb, S);
  softmax_causal<<<SEQQ, 256, 0, stream>>>(S);
  gemm_pv_split<<<dim3(4, 16, 4), 512, 0, stream>>>(S, Vt, out, part);
  reduce_pv<<<3072, 256, 0, stream>>>(out, part);
}

// Round 13
// 128.490 us; speedup vs baseline: 8.5592x; 8.5592x over previous
//
#include <hip/hip_runtime.h>
#include <hip/hip_bf16.h>
#include <cstdint>
#include <cstddef>

// SelfAttentionV2: x[4096,1024] fp32; Wq/Wk/Wv [1024,1024] fp32.
// out = softmax(causal((x Wq^T)(x Wk^T)^T / 32)) @ (x Wv^T), fp32 out.
//
// GEMM: faithful port of the verified 256^2 8-phase template (m201) onto the
// proven [256][32]-slab LDS layout. 8 waves (2M x 4N -> per-wave 128x64,
// acc[8][4]), K-tiles of BK=64 stored as 2 slabs [256 r][32 c] (kk=0,1),
// 2 LDS slots (A 2x32KB + B 2x32KB = 128KB). Iteration = 2 K-tiles, 8 phases.
// Phase = { ds_reads (0/4/12 b128) | 2 gload_lds | [vmcnt] -> barrier ->
//           setprio(1) 16 MFMA (one C-quadrant x K=64) setprio(0) -> barrier }.
// Quadrants: ph1..4 = tile 2i (slot0): (mh0,np0),(mh0,np1),(mh1,np0),(mh1,np1);
// ph5..8 same for tile 2i+1 (slot1). Staging (2 gloads/phase):
//   ph1-3: tile 2i+1 quarters q1,q2,q3 -> slot1   (q0 staged at ph8 prev iter)
//   ph4-7: tile 2i+2 quarters q0..q3   -> slot0
//   ph8:   tile 2i+3 quarter  q0       -> slot1
// Counted waits ONLY at ph4 and ph8: vmcnt(2) = "everything but the 2 loads
// just issued has landed" -> validates the next tile's 8 stages. Last-iter
// variants: vmcnt(0)@ph4, none@ph8.
// Hazard proof: (a) read-validity: tile T's stages are all older than the
// vmcnt(2) in the phase preceding T's first read; each wave waits before the
// barrier, so after the barrier ALL waves' stages landed. (b) write-safety:
// a stage into slot s issues >=1 phase after the last ds_read phase of the
// slot's previous tile; those reads drained before that phase's trailing
// barrier (compiler emits lgkmcnt before the MFMA that consumes them), and
// the stage issues only after every wave passed that barrier.
// Swizzle (proven 0-conflict R2-R11): source col byte ^ ((row&8)?32:0) on
// stage (global_load_lds writes linearly); ds_read offset o ^= ((o>>9)&1)<<5.

#define SEQQ 4096
#define DDIM 1024

typedef __bf16 bf16x8 __attribute__((ext_vector_type(8)));
typedef float f32x4 __attribute__((ext_vector_type(4)));

__device__ __forceinline__ unsigned short f2bf(float f) {
  unsigned int u = __builtin_bit_cast(unsigned int, f);
  unsigned int r = u + 0x7FFFu + ((u >> 16) & 1u);  // RNE; -inf stays -inf
  return (unsigned short)(r >> 16);
}

__device__ __forceinline__ void gload_lds16(const void* g, void* lds) {
  __builtin_amdgcn_global_load_lds(
      (__attribute__((address_space(1))) void*)(uintptr_t)g,
      (__attribute__((address_space(3))) void*)(uintptr_t)lds, 16, 0, 0);
}

// ---- fused fp32 -> bf16 conversion (x, Wq*1/32, Wk, Wv) ----
__global__ __launch_bounds__(256) void cvt_all(const float* __restrict__ x,
                                               const float* __restrict__ Wq,
                                               const float* __restrict__ Wk,
                                               const float* __restrict__ Wv,
                                               unsigned short* __restrict__ xb,
                                               unsigned short* __restrict__ Wcat) {
  int b = blockIdx.x;
  const float* src;
  unsigned short* dst;
  float scale = 1.0f;
  if (b < 4096) {
    src = x; dst = xb;
  } else if (b < 5120) {
    src = Wq; dst = Wcat; scale = 0.03125f; b -= 4096;
  } else if (b < 6144) {
    src = Wk; dst = Wcat + (1u << 20); b -= 5120;
  } else {
    src = Wv; dst = Wcat + (2u << 20); b -= 6144;
  }
  const int i = (b * 256 + threadIdx.x) * 4;
  const float4 v = *reinterpret_cast<const float4*>(src + i);
  ushort4 o;
  o.x = f2bf(v.x * scale);
  o.y = f2bf(v.y * scale);
  o.z = f2bf(v.z * scale);
  o.w = f2bf(v.w * scale);
  *reinterpret_cast<ushort4*>(dst + i) = o;
}

// ---- 256x256 8-phase GEMM core ----
#define GEMM_PRE()                                                          \
  __shared__ unsigned short As[2][16384] __attribute__((aligned(16)));      \
  __shared__ unsigned short Bs[2][16384] __attribute__((aligned(16)));      \
  const int tid = threadIdx.x;                                              \
  const int wave = tid >> 6, lane = tid & 63;                               \
  const int wr = (wave >> 2) * 128, wc = (wave & 3) * 64;                   \
  f32x4 acc[8][4] = {};                                                     \
  int offA[8], offB[4];                                                     \
  {                                                                         \
    const int cb = (lane >> 4) * 16;                                        \
    const int rA = wr + (lane & 15);                                        \
    _Pragma("unroll")                                                       \
    for (int m = 0; m < 8; ++m) {                                           \
      int o = (rA + m * 16) * 64 + cb;                                      \
      offA[m] = o ^ (((o >> 9) & 1) << 5);                                  \
    }                                                                       \
    const int rB = wc + (lane & 15);                                        \
    _Pragma("unroll")                                                       \
    for (int n = 0; n < 4; ++n) {                                           \
      int o = (rB + n * 16) * 64 + cb;                                      \
      offB[n] = o ^ (((o >> 9) & 1) << 5);                                  \
    }                                                                       \
  }

#define BAR asm volatile("s_barrier" ::: "memory")

#define RD_A(SLOT, MH)                                                     \
  _Pragma("unroll")                                                        \
  for (int mm = 0; mm < 4; ++mm)                                           \
    _Pragma("unroll")                                                      \
    for (int kk = 0; kk < 2; ++kk)                                         \
      aF[mm][kk] = *(const bf16x8*)(ldsA + (SLOT) * 32768 + kk * 16384 +   \
                                    offA[(MH) * 4 + mm]);

#define RD_B(SLOT, NP, BS)                                                 \
  _Pragma("unroll")                                                        \
  for (int nn = 0; nn < 2; ++nn)                                           \
    _Pragma("unroll")                                                      \
    for (int kk = 0; kk < 2; ++kk)                                         \
      BS[nn][kk] = *(const bf16x8*)(ldsB + (SLOT) * 32768 + kk * 16384 +   \
                                    offB[(NP) * 2 + nn]);

#define MFMA16(MH, NP, BS)                                                 \
  __builtin_amdgcn_s_setprio(1);                                           \
  _Pragma("unroll")                                                        \
  for (int kk = 0; kk < 2; ++kk)                                           \
    _Pragma("unroll")                                                      \
    for (int mm = 0; mm < 4; ++mm)                                         \
      _Pragma("unroll")                                                    \
      for (int nn = 0; nn < 2; ++nn)                                       \
        acc[(MH) * 4 + mm][(NP) * 2 + nn] =                                \
            __builtin_amdgcn_mfma_f32_16x16x32_bf16(                       \
                aF[mm][kk], BS[nn][kk],                                    \
                acc[(MH) * 4 + mm][(NP) * 2 + nn], 0, 0, 0);               \
  __builtin_amdgcn_s_setprio(0);

// Stage quarter Q (0:Akk0 1:Akk1 2:Bkk0 3:Bkk1) of the tile whose source
// K-byte-offset is KOFS into slot SLOT. 2 gload_lds (halves h0,h1).
#define STGQ(SLOT, KOFS, Q)                                                \
  {                                                                        \
    const int lofs = (SLOT) * 32768 + ((Q) & 1) * 16384 + wave * 1024;     \
    const int sofs = (KOFS) + ((Q) & 1) * 64;                              \
    if ((Q) < 2) {                                                         \
      gload_lds16(bA0 + sofs, ldsA + lofs);                                \
      gload_lds16(bA1 + sofs, ldsA + lofs + 8192);                         \
    } else {                                                               \
      gload_lds16(bB0 + sofs, ldsB + lofs);                                \
      gload_lds16(bB1 + sofs, ldsB + lofs + 8192);                         \
    }                                                                      \
  }

// S0,S1 in BK=64 tile units; (S1-S0) must be EVEN and >= 2.
#define GEMM_LOOP(ABASE, LDA, BBASE, LDB, S0, S1)                          \
  do {                                                                     \
    const int ni = ((S1) - (S0)) >> 1;                                     \
    const size_t lda2 = (size_t)(LDA) * 2, ldb2 = (size_t)(LDB) * 2;       \
    const int srow = wave * 16 + (lane >> 2);                              \
    const int scb = ((lane & 3) * 16) ^ (((lane >> 5) & 1) << 5);          \
    const char* bA0 = (const char*)(ABASE) + (size_t)srow * lda2 +         \
                      (size_t)(S0) * 128 + scb;                            \
    const char* bA1 = bA0 + 128 * lda2;                                    \
    const char* bB0 = (const char*)(BBASE) + (size_t)srow * ldb2 +         \
                      (size_t)(S0) * 128 + scb;                            \
    const char* bB1 = bB0 + 128 * ldb2;                                    \
    char* ldsA = (char*)&As[0][0];                                         \
    char* ldsB = (char*)&Bs[0][0];                                         \
    bf16x8 aF[4][2], b0[2][2], b1[2][2];                                   \
    /* prologue: tile0 fully + tile1 q0 */                                 \
    STGQ(0, 0, 0); STGQ(0, 0, 1); STGQ(0, 0, 2); STGQ(0, 0, 3);            \
    STGQ(1, 128, 0);                                                       \
    asm volatile("s_waitcnt vmcnt(2)" ::: "memory");                       \
    BAR;                                                                   \
    for (int i = 0; i < ni; ++i) {                                         \
      const int k0 = i * 256;                                              \
      const bool st = (i + 1 < ni);                                        \
      /* ph1 */                                                            \
      RD_A(0, 0); RD_B(0, 0, b0);                                          \
      STGQ(1, k0 + 128, 1);                                                \
      BAR; MFMA16(0, 0, b0); BAR;                                          \
      /* ph2 */                                                            \
      RD_B(0, 1, b1);                                                      \
      STGQ(1, k0 + 128, 2);                                                \
      BAR; MFMA16(0, 1, b1); BAR;                                          \
      /* ph3 */                                                            \
      RD_A(0, 1);                                                          \
      STGQ(1, k0 + 128, 3);                                                \
      BAR; MFMA16(1, 0, b0); BAR;                                          \
      /* ph4 */                                                            \
      if (st) {                                                            \
        STGQ(0, k0 + 256, 0);                                              \
        asm volatile("s_waitcnt vmcnt(2)" ::: "memory");                   \
      } else {                                                             \
        asm volatile("s_waitcnt vmcnt(0)" ::: "memory");                   \
      }                                                                    \
      BAR; MFMA16(1, 1, b1); BAR;                                          \
      /* ph5 */                                                            \
      RD_A(1, 0); RD_B(1, 0, b0);                                          \
      if (st) STGQ(0, k0 + 256, 1);                                        \
      BAR; MFMA16(0, 0, b0); BAR;                                          \
      /* ph6 */                                                            \
      RD_B(1, 1, b1);                                                      \
      if (st) STGQ(0, k0 + 256, 2);                                        \
      BAR; MFMA16(0, 1, b1); BAR;                                          \
      /* ph7 */                                                            \
      RD_A(1, 1);                                                          \
      if (st) STGQ(0, k0 + 256, 3);                                        \
      BAR; MFMA16(1, 0, b0); BAR;                                          \
      /* ph8 */                                                            \
      if (st) {                                                            \
        STGQ(1, k0 + 384, 0);                                              \
        asm volatile("s_waitcnt vmcnt(2)" ::: "memory");                   \
        BAR;                                                               \
        MFMA16(1, 1, b1);                                                  \
        BAR;                                                               \
      } else {                                                             \
        MFMA16(1, 1, b1);                                                  \
      }                                                                    \
    }                                                                      \
  } while (0)

// ---- QKV: C[4096,3072] = xb @ Wcat^T; Q,K row-major; V transposed ----
__global__ __launch_bounds__(512, 1) void gemm_qkv(const unsigned short* __restrict__ X,
                                                   const unsigned short* __restrict__ W,
                                                   unsigned short* __restrict__ Qb,
                                                   unsigned short* __restrict__ Kb,
                                                   unsigned short* __restrict__ Vt) {
  GEMM_PRE();
  const int brow = blockIdx.y * 256, bcol = blockIdx.x * 256;
  GEMM_LOOP(X + (size_t)brow * DDIM, DDIM, W + (size_t)bcol * DDIM, DDIM, 0, 16);
  const int region = bcol >> 10;  // 0=Q 1=K 2=V
  const int lcol = bcol & 1023;
  const int c0 = wc + (lane & 15);
  const int r0 = wr + ((lane >> 4) << 2);
  if (region < 2) {
    unsigned short* dst = (region == 0) ? Qb : Kb;
#pragma unroll
    for (int m = 0; m < 8; ++m) {
      const int r = brow + r0 + m * 16;
#pragma unroll
      for (int n = 0; n < 4; ++n) {
        const int c = lcol + c0 + n * 16;
#pragma unroll
        for (int j = 0; j < 4; ++j)
          dst[(size_t)(r + j) * DDIM + c] = f2bf(acc[m][n][j]);
      }
    }
  } else {
#pragma unroll
    for (int m = 0; m < 8; ++m) {
      const int r = brow + r0 + m * 16;
#pragma unroll
      for (int n = 0; n < 4; ++n) {
        const int c = lcol + c0 + n * 16;
        ushort4 pk;
        pk.x = f2bf(acc[m][n][0]);
        pk.y = f2bf(acc[m][n][1]);
        pk.z = f2bf(acc[m][n][2]);
        pk.w = f2bf(acc[m][n][3]);
        *reinterpret_cast<ushort4*>(Vt + (size_t)c * SEQQ + r) = pk;
      }
    }
  }
}

// ---- QK^T: S = Qb @ Kb^T, lower-triangle 256-tiles, causal mask ----
__global__ __launch_bounds__(512, 1) void gemm_qkt(const unsigned short* __restrict__ Qb,
                                                   const unsigned short* __restrict__ Kb,
                                                   unsigned short* __restrict__ S) {
  const int bi = blockIdx.y, bj = blockIdx.x;
  if (bj > bi) return;
  GEMM_PRE();
  const int brow = bi * 256, bcol = bj * 256;
  GEMM_LOOP(Qb + (size_t)brow * DDIM, DDIM, Kb + (size_t)bcol * DDIM, DDIM, 0, 16);
  const int c0 = wc + (lane & 15);
  const int r0 = wr + ((lane >> 4) << 2);
#pragma unroll
  for (int m = 0; m < 8; ++m) {
    const int r = brow + r0 + m * 16;
#pragma unroll
    for (int n = 0; n < 4; ++n) {
      const int c = bcol + c0 + n * 16;
#pragma unroll
      for (int j = 0; j < 4; ++j) {
        unsigned short o = (c > r + j) ? (unsigned short)0xFF80  // -inf bf16
                                       : f2bf(acc[m][n][j]);
        S[(size_t)(r + j) * SEQQ + c] = o;
      }
    }
  }
}

// ---- row softmax over causal prefix (256-padded), in place ----
__global__ __launch_bounds__(256) void softmax_causal(unsigned short* __restrict__ S) {
  const int row = blockIdx.x;
  const int L = ((row >> 8) + 1) << 8;  // 256-padded: matches PV K-extent
  unsigned short* Srow = S + (size_t)row * SEQQ;
  __shared__ float red[4];
  const int tid = threadIdx.x;
  const int lane = tid & 63, wave = tid >> 6;

  float x[16];
  bool have[2];
  float m = -3.0e38f;
#pragma unroll
  for (int it = 0; it < 2; ++it) {
    const int j = tid * 8 + it * 2048;
    have[it] = (j < L);
    if (have[it]) {
      const uint4 v = *reinterpret_cast<const uint4*>(Srow + j);
      const unsigned u[4] = {v.x, v.y, v.z, v.w};
#pragma unroll
      for (int q = 0; q < 4; ++q) {
        x[it * 8 + q * 2] = __builtin_bit_cast(float, u[q] << 16);
        x[it * 8 + q * 2 + 1] = __builtin_bit_cast(float, u[q] & 0xFFFF0000u);
      }
#pragma unroll
      for (int q = 0; q < 8; ++q) m = fmaxf(m, x[it * 8 + q]);
    }
  }
#pragma unroll
  for (int o = 32; o; o >>= 1) m = fmaxf(m, __shfl_xor(m, o));
  if (lane == 0) red[wave] = m;
  __syncthreads();
  m = fmaxf(fmaxf(red[0], red[1]), fmaxf(red[2], red[3]));
  __syncthreads();

  float sum = 0.f;
#pragma unroll
  for (int it = 0; it < 2; ++it)
    if (have[it]) {
#pragma unroll
      for (int q = 0; q < 8; ++q) {
        x[it * 8 + q] = __expf(x[it * 8 + q] - m);  // exp(-inf)=0 for masked
        sum += x[it * 8 + q];
      }
    }
#pragma unroll
  for (int o = 32; o; o >>= 1) sum += __shfl_xor(sum, o);
  if (lane == 0) red[wave] = sum;
  __syncthreads();
  sum = red[0] + red[1] + red[2] + red[3];
  const float inv = 1.0f / sum;

#pragma unroll
  for (int it = 0; it < 2; ++it)
    if (have[it]) {
      const int j = tid * 8 + it * 2048;
      unsigned u[4];
#pragma unroll
      for (int q = 0; q < 4; ++q) {
        u[q] = (unsigned)f2bf(x[it * 8 + q * 2] * inv) |
               ((unsigned)f2bf(x[it * 8 + q * 2 + 1] * inv) << 16);
      }
      *reinterpret_cast<uint4*>(Srow + j) = make_uint4(u[0], u[1], u[2], u[3]);
    }
}

// ---- split-K helpers for PV (256-row blocks bi=0..15) ----
__device__ __forceinline__ int pv_nc(int bi) { return (bi >> 2) + 1; }
__device__ __forceinline__ int pv_rcbase(int bi) {
  const int g = bi >> 2, r = bi & 3;
  return 2 * g * (g - 1) + r * g;
}

// ---- PV: out/partials = P @ Vt^T, causal K-range, split-K (even chunks) ----
__global__ __launch_bounds__(512, 1) void gemm_pv_split(const unsigned short* __restrict__ P,
                                                        const unsigned short* __restrict__ Vt,
                                                        float* __restrict__ O,
                                                        float* __restrict__ part) {
  const int bj = blockIdx.x, bi = blockIdx.y, ck = blockIdx.z;
  const int nc = pv_nc(bi);
  if (ck >= nc) return;
  const int kt = (bi + 1) * 4;                        // K-tiles of 64 elems
  const int W = 2 * ((kt + 2 * nc - 1) / (2 * nc));   // even chunk width
  const int s0 = ck * W;
  const int s1 = min(s0 + W, kt);
  if (s0 >= s1) return;

  GEMM_PRE();
  const int brow = bi * 256, bcol = bj * 256;
  GEMM_LOOP(P + (size_t)brow * SEQQ, SEQQ, Vt + (size_t)bcol * SEQQ, SEQQ, s0, s1);
  const int c0 = wc + (lane & 15);
  const int r0 = wr + ((lane >> 4) << 2);
  if (ck == 0) {
#pragma unroll
    for (int m = 0; m < 8; ++m) {
      const int r = brow + r0 + m * 16;
#pragma unroll
      for (int n = 0; n < 4; ++n) {
        const int c = bcol + c0 + n * 16;
#pragma unroll
        for (int j = 0; j < 4; ++j)
          O[(size_t)(r + j) * DDIM + c] = acc[m][n][j];
      }
    }
  } else {
    float* tile = part + ((size_t)(pv_rcbase(bi) + (ck - 1)) * 4 + bj) * 65536;
#pragma unroll
    for (int m = 0; m < 8; ++m) {
      const int lr = r0 + m * 16;
#pragma unroll
      for (int n = 0; n < 4; ++n) {
        const int lc = c0 + n * 16;
#pragma unroll
        for (int j = 0; j < 4; ++j)
          tile[(lr + j) * 256 + lc] = acc[m][n][j];
      }
    }
  }
}

// ---- add partial tiles into out rows >= 1024 ----
__global__ __launch_bounds__(256) void reduce_pv(float* __restrict__ O,
                                                 const float* __restrict__ part) {
  const int idx = blockIdx.x * 256 + threadIdx.x;   // one float4 per thread
  const int r = 1024 + (idx >> 8);                  // 256 float4s per row
  const int cc = (idx & 255) * 4;
  const int bi = r >> 8;
  const int nparts = bi >> 2;                       // nc-1
  const int rcb = pv_rcbase(bi);
  const int bj = cc >> 8;
  const int lr = r & 255, lc = cc & 255;
  float4 acc = *reinterpret_cast<float4*>(O + (size_t)r * DDIM + cc);
  for (int k = 0; k < nparts; ++k) {
    const float4 p = *reinterpret_cast<const float4*>(
        part + ((size_t)(rcb + k) * 4 + bj) * 65536 + lr * 256 + lc);
    acc.x += p.x; acc.y += p.y; acc.z += p.z; acc.w += p.w;
  }
  *reinterpret_cast<float4*>(O + (size_t)r * DDIM + cc) = acc;
}

extern "C" void kernel_launch(void* const* d_in, const int* in_sizes, int n_in,
                              void* d_out, int out_size, void* d_ws, size_t ws_size,
                              hipStream_t stream) {
  (void)in_sizes; (void)n_in; (void)out_size; (void)ws_size;
  const float* x = (const float*)d_in[0];
  const float* Wq = (const float*)d_in[1];
  const float* Wk = (const float*)d_in[2];
  const float* Wv = (const float*)d_in[3];
  float* out = (float*)d_out;

  char* ws = (char*)d_ws;
  unsigned short* xb   = (unsigned short*)(ws);                        //  8 MB [4096,1024]
  unsigned short* Wcat = (unsigned short*)(ws + ((size_t)8 << 20));    //  6 MB [3072,1024]
  unsigned short* Qb   = (unsigned short*)(ws + ((size_t)14 << 20));   //  8 MB [4096,1024]
  unsigned short* Kb   = (unsigned short*)(ws + ((size_t)22 << 20));   //  8 MB [4096,1024]
  unsigned short* Vt   = (unsigned short*)(ws + ((size_t)30 << 20));   //  8 MB [1024,4096]
  unsigned short* S    = (unsigned short*)(ws + ((size_t)38 << 20));   // 32 MB [4096,4096]
  float* part = (float*)ws;  // 24 MB fp32 partials; reuses dead xb/Wcat/Qb/Kb region

  cvt_all<<<7168, 256, 0, stream>>>(x, Wq, Wk, Wv, xb, Wcat);
  gemm_qkv<<<dim3(12, 16), 512, 0, stream>>>(xb, Wcat, Qb, Kb, Vt);
  gemm_qkt<<<dim3(16, 16), 512, 0, stream>>>(Qb, Kb, S);
  softmax_causal<<<SEQQ, 256, 0, stream>>>(S);
  gemm_pv_split<<<dim3(4, 16, 4), 512, 0, stream>>>(S, Vt, out, part);
  reduce_pv<<<3072, 256, 0, stream>>>(out, part);
}